// Round 7
// baseline (324.734 us; speedup 1.0000x reference)
//
#include <hip/hip_runtime.h>
#include <hip/hip_bf16.h>
#include <stdint.h>

typedef __attribute__((ext_vector_type(8))) short short8;
typedef __attribute__((ext_vector_type(4))) float floatx4;
typedef __attribute__((ext_vector_type(2))) float floatx2;
typedef __attribute__((ext_vector_type(2))) int intx2;
typedef __hip_bfloat16 bf16;

__device__ __forceinline__ float b2f(bf16 v) { return __bfloat162float(v); }
__device__ __forceinline__ bf16 f2b(float v) { return __float2bfloat16(v); }
__device__ __forceinline__ float gelu_f(float v) {
    return 0.5f * v * (1.0f + erff(v * 0.70710678118654752f));
}
// two packed bf16 (one dword) -> two fp32, exact (<<16)
__device__ __forceinline__ floatx2 cvt2(unsigned v) {
    floatx2 r;
    r.x = __uint_as_float(v << 16);
    r.y = __uint_as_float(v & 0xffff0000u);
    return r;
}
// VALU-rate cross-lane add via DPP (no LGKM). CTRL: 0xB1=quad xor1, 0x4E=quad xor2,
// 0x141=row_half_mirror (cross-quad within 8-lane group; groups are 8-aligned).
template <int CTRL>
__device__ __forceinline__ float dpp_add(float v) {
    int x = __builtin_amdgcn_update_dpp(0, __float_as_int(v), CTRL, 0xf, 0xf, true);
    return v + __int_as_float(x);
}
// full-wave half sum at VALU rate: v[l] + v[l^32] for every lane.
// permlane32_swap returns (vdst', vsrc'); with both inputs = v, one output holds v
// and the other holds the cross-half value (per lane), so their sum is total.
__device__ __forceinline__ float sum_halves(float v) {
#if __has_builtin(__builtin_amdgcn_permlane32_swap)
    intx2 r = __builtin_amdgcn_permlane32_swap(__float_as_int(v), __float_as_int(v),
                                               false, false);
    return __int_as_float(r.x) + __int_as_float(r.y);
#else
    return v + __shfl_xor(v, 32, 64);
#endif
}

#define GLD_LDS16(gptr, lptr) \
  __builtin_amdgcn_global_load_lds((const __attribute__((address_space(1))) void*)(gptr), \
                                   (__attribute__((address_space(3))) void*)(lptr), 16, 0, 0)

// NOTE (R12): cooperative grid.sync() costs ~60us each here -- never fuse via grid.sync.
// NOTE (R15): GEMM LDS conflicts: fragment reads, fixed by XOR-swizzled 16B chunks
// (physical slot = logical ^ (row&7)); global_load_lds dest is linear, so swizzle the
// SOURCE k-offset.
// NOTE (R16): x pre-converted to bf16; GEMM = bf16 global_load_lds path; GEMM epilogue
// in two 64-row halves -> LDS exactly 32 KB.
// NOTE (R17, FAILED): deep gather prefetch adds movs/iter -> slower. No added per-lane
// state in the k_agg loop.  NOTE (R20b, FAILED): 16 lanes/edge -> VGPR 56, occ 38%.
// NOTE (R18, FAILED): node-grain work-steal = 32768 same-address atomics = 460us wall.
// NOTE (R19): 128-thread blocks; k_agg is instruction-issue-bound (VALU ~71%).
// NOTE (R21): leaky=max(u,0.2u); att pre-scaled by log2e -> raw v_exp_f32. KEEP.
// NOTE (R22): bucket CSR (64 slots/node): scatter needs no offsets -- the atomic
// return IS the slot. Deletes k_scan (single-block serializer), count role, rank/fill
// buffers. Scatter overlaps the convert/transpose kernel; GEMM kernels are pure.
// k_agg epilogue via permlane32_swap (VALU) instead of 9 ds_bpermute shfl_xor(32).

// ---------------- fused: bucket scatter (0..511) + weight transposes (512..1535) + x->bf16 (1536..2559) ----------------
__global__ void k_tr_scatter(const int* __restrict__ dst, const int* __restrict__ src,
                             int* __restrict__ cnt, int* __restrict__ col, int E,
                             const float* __restrict__ Wl1, const float* __restrict__ Wr1,
                             const float* __restrict__ Wl2, const float* __restrict__ Wr2,
                             bf16* __restrict__ Wt,
                             const float* __restrict__ x, bf16* __restrict__ xb) {
    int bx = blockIdx.x;
    if (bx < 512) {
        int g = bx * 256 + threadIdx.x;
        if (g * 4 < E) {
            int4 d = ((const int4*)dst)[g];
            int4 s = ((const int4*)src)[g];
            int rk;
            rk = atomicAdd(&cnt[d.x], 1); if (rk < 64) col[(d.x << 6) + rk] = s.x;
            rk = atomicAdd(&cnt[d.y], 1); if (rk < 64) col[(d.y << 6) + rk] = s.y;
            rk = atomicAdd(&cnt[d.z], 1); if (rk < 64) col[(d.z << 6) + rk] = s.z;
            rk = atomicAdd(&cnt[d.w], 1); if (rk < 64) col[(d.w << 6) + rk] = s.w;
        }
    } else if (bx < 1536) {
        int b = bx - 512;
        int r = b & 255, half = (b >> 8) & 1, layer = b >> 9;
        int c = threadIdx.x;
        const float* W = layer ? (half ? Wr2 : Wl2) : (half ? Wr1 : Wl1);
        Wt[(size_t)(layer * 512 + half * 256 + c) * 256 + r] = f2b(W[r * 256 + c]);
    } else {
        // x (32768x256 fp32) -> bf16, 32 contiguous floats per thread
        int b = bx - 1536;
        size_t base = ((size_t)b * 256 + threadIdx.x) * 32;
        const float4* xin = (const float4*)(x + base);
        #pragma unroll
        for (int q = 0; q < 4; q++) {
            float4 a = xin[2 * q];
            float4 c = xin[2 * q + 1];
            bf16 t[8] = {f2b(a.x), f2b(a.y), f2b(a.z), f2b(a.w),
                         f2b(c.x), f2b(c.y), f2b(c.z), f2b(c.w)};
            *(short8*)(xb + base + q * 8) = *(const short8*)t;
        }
    }
}

// ---------------- GEMM tile body: C[M,512] = A[M,K] @ Bt[512,K]^T + bias ----------------
// 128x128 tile, BK=64, XOR-swizzled LDS (physical 16B chunk = logical ^ (row&7)).
// bf16 A only (global_load_lds both operands). LDS = 32768 B exactly (5 blocks/CU).
__global__ __launch_bounds__(256) void k_gemm(const bf16* __restrict__ A,
                                              const bf16* __restrict__ Bt,
                                              const float* __restrict__ biasL,
                                              const float* __restrict__ biasR,
                                              bf16* __restrict__ C, int K) {
    __shared__ bf16 smem[16384];
    bf16* As = smem;
    bf16* Bs = smem + 8192;
    const int n0 = blockIdx.x * 128;
    const int m0 = blockIdx.y * 128;
    const int tid  = threadIdx.x;
    const int wave = tid >> 6;
    const int lane = tid & 63;
    const int quad = lane >> 4;
    const int l16  = lane & 15;
    const int wm = (wave & 1) * 64;
    const int wn = (wave >> 1) * 64;
    // source k-offset for swizzled global_load_lds staging (dest slot lane&7, row lane>>3)
    const int scole = ((lane & 7) ^ (lane >> 3)) * 8;
    const int srow  = lane >> 3;

    floatx4 acc[4][4] = {};

    for (int k0 = 0; k0 < K; k0 += 64) {
        #pragma unroll
        for (int i = 0; i < 4; i++) {
            int chunk = i * 4 + wave;                 // 16 chunks of 1 KB (8 rows) each
            int row = chunk * 8 + srow;
            GLD_LDS16(A + (size_t)(m0 + row) * K + k0 + scole,
                      (char*)As + chunk * 1024 + lane * 16);
            GLD_LDS16(Bt + (size_t)(n0 + row) * K + k0 + scole,
                      (char*)Bs + chunk * 1024 + lane * 16);
        }
        __syncthreads();
        #pragma unroll
        for (int ks = 0; ks < 2; ks++) {
            short8 af[4], bfr[4];
            int pk = ((ks * 4 + quad) ^ (l16 & 7)) * 8;   // swizzled fragment k-offset
            #pragma unroll
            for (int i = 0; i < 4; i++) {
                af[i]  = *(const short8*)&As[(wm + i * 16 + l16) * 64 + pk];
                bfr[i] = *(const short8*)&Bs[(wn + i * 16 + l16) * 64 + pk];
            }
            #pragma unroll
            for (int i = 0; i < 4; i++)
                #pragma unroll
                for (int j = 0; j < 4; j++)
                    acc[i][j] = __builtin_amdgcn_mfma_f32_16x16x32_bf16(af[i], bfr[j], acc[i][j], 0, 0, 0);
        }
        __syncthreads();
    }

    // C/D layout: col = lane&15, row = quad*4 + reg  [verified m89/m91]
    // Two 64-row halves through a 64x136 LDS buffer (fits in As+Bs region).
    float bvj[4];
    #pragma unroll
    for (int j = 0; j < 4; j++) {
        int gcol = n0 + wn + j * 16 + l16;
        bvj[j] = (gcol < 256) ? biasL[gcol] : biasR[gcol - 256];
    }
    #pragma unroll
    for (int h = 0; h < 2; h++) {
        if ((wave & 1) == h) {
            #pragma unroll
            for (int j = 0; j < 4; j++) {
                int lcol = wn + j * 16 + l16;
                #pragma unroll
                for (int i = 0; i < 4; i++)
                    #pragma unroll
                    for (int r = 0; r < 4; r++)
                        smem[(i * 16 + quad * 4 + r) * 136 + lcol] = f2b(acc[i][j][r] + bvj[j]);
            }
        }
        __syncthreads();
        {
            int rl = tid >> 4;
            int cs = (tid & 15) * 8;
            #pragma unroll
            for (int p = 0; p < 4; p++) {
                int row = p * 16 + rl;
                short8 v = *(const short8*)&smem[row * 136 + cs];
                *(short8*)(C + (size_t)(m0 + h * 64 + row) * 512 + n0 + cs) = v;
            }
        }
        if (h == 0) __syncthreads();
    }
}

// ---------------- GATv2 aggregation: half-wave per edge, 8 ch/lane, packed fp32 math ----------
// 128-thread blocks, one wave per dst node. Lanes 0-31 = item a, 32-63 = item b of each
// pair. Within a half: 8 lanes per head (hl>>3), 8 channels per lane ((hl&7)*8).
// Item 0 = self-loop. Bucket CSR: node i's in-edges at col[i*64 .. i*64+deg).
// Max-free softmax (logits bounded). leaky = max(u, 0.2u); att pre-scaled by log2(e)
// so p = v_exp_f32(l) = e^logit. Reduce via DPP; half-combine via permlane32_swap.
__global__ __launch_bounds__(128) void k_agg(const bf16* __restrict__ xlr,
                                             const float* __restrict__ att,
                                             const int* __restrict__ cnt,
                                             const int* __restrict__ col,
                                             const float* __restrict__ bias,
                                             bf16* __restrict__ out, int do_gelu) {
    int wave = threadIdx.x >> 6, lane = threadIdx.x & 63;
    int i = blockIdx.x * 2 + wave;
    int hl = lane & 31;
    int half = lane >> 5;
    unsigned f = (hl >> 3) * 64 + (hl & 7) * 8;

    const float LOG2E = 1.4426950408889634f;
    const floatx2 c02 = {0.2f, 0.2f};
    floatx2 attv[4], xrv[4];
    {
        floatx4 a0 = *(const floatx4*)(att + f);
        floatx4 a1 = *(const floatx4*)(att + f + 4);
        attv[0] = (floatx2){LOG2E * a0[0], LOG2E * a0[1]};
        attv[1] = (floatx2){LOG2E * a0[2], LOG2E * a0[3]};
        attv[2] = (floatx2){LOG2E * a1[0], LOG2E * a1[1]};
        attv[3] = (floatx2){LOG2E * a1[2], LOG2E * a1[3]};
        unsigned raw[4];
        *(uint4*)raw = *(const uint4*)(xlr + ((unsigned)i * 512u + 256u + f));
        #pragma unroll
        for (int k = 0; k < 4; k++) xrv[k] = cvt2(raw[k]);
    }

    int deg = cnt[i];
    deg = deg > 64 ? 64 : deg;
    int e0 = i << 6;
    int total = 1 + deg;   // self + in-edges

    int src_c = i;
    if (half == 1 && total > 1) src_c = col[e0];
    unsigned g_cur[4];
    *(uint4*)g_cur = *(const uint4*)(xlr + ((unsigned)src_c * 512u + f));
    int t1 = 2 + half;
    int src_n = (t1 < total) ? col[e0 + t1 - 1] : i;

    float s = 0.f;
    floatx2 acc2[4] = {};

    for (int base = 0; base < total; base += 2) {
        unsigned g_nxt[4];
        *(uint4*)g_nxt = *(const uint4*)(xlr + ((unsigned)src_n * 512u + f));
        int t2 = base + 4 + half;
        int src_n2 = (t2 < total) ? col[e0 + t2 - 1] : i;
        bool valid = (base + half) < total;
        floatx2 xv[4], l2 = {0.f, 0.f};
        #pragma unroll
        for (int k = 0; k < 4; k++) {
            xv[k] = cvt2(g_cur[k]);
            floatx2 u = xv[k] + xrv[k];                    // v_pk_add_f32
            floatx2 lr = __builtin_elementwise_max(u, u * c02);  // leaky: pk_mul + pk_max
            l2 += lr * attv[k];                            // v_pk_fma_f32 (att * log2e)
        }
        float l = l2.x + l2.y;
        l = dpp_add<0xB1>(l);     // xor1 within quad
        l = dpp_add<0x4E>(l);     // xor2 within quad
        l = dpp_add<0x141>(l);    // cross-quad within 8-lane group
        float p;
        asm("v_exp_f32 %0, %1" : "=v"(p) : "v"(l));   // 2^(logit*log2e) = e^logit
        p = valid ? p : 0.f;
        s += p;
        floatx2 p2 = {p, p};
        #pragma unroll
        for (int k = 0; k < 4; k++) acc2[k] += p2 * xv[k];   // v_pk_fma_f32
        #pragma unroll
        for (int k = 0; k < 4; k++) g_cur[k] = g_nxt[k];
        src_n = src_n2;
    }

    // combine the two halves (VALU-rate, no LGKM)
    s = sum_halves(s);
    #pragma unroll
    for (int k = 0; k < 4; k++) {
        acc2[k].x = sum_halves(acc2[k].x);
        acc2[k].y = sum_halves(acc2[k].y);
    }

    if (half == 0) {
        float inv = 1.0f / (s + 1e-16f);
        bf16 ov[8];
        #pragma unroll
        for (int k = 0; k < 4; k++) {
            float v0 = acc2[k].x * inv + bias[f + 2 * k];
            float v1 = acc2[k].y * inv + bias[f + 2 * k + 1];
            if (do_gelu) { v0 = gelu_f(v0); v1 = gelu_f(v1); }
            ov[2 * k]     = f2b(v0);
            ov[2 * k + 1] = f2b(v1);
        }
        *(short8*)(out + ((unsigned)i * 256u + f)) = *(const short8*)ov;
    }
}

// ---------------- shared head-layer body (block = one (graph, 64-col chunk)) ----------------
__device__ __forceinline__ void head_body(const bf16* __restrict__ inB,
                                          const float* __restrict__ inF,
                                          const float* __restrict__ W,
                                          const float* __restrict__ bias,
                                          float* __restrict__ out,
                                          int K, int N, long long row_stride, int act,
                                          int g, int chunk, float* zin, float* red) {
    int t = threadIdx.x;
    int nc = t & 63;
    int kq = t >> 6;
    int n = chunk * 64 + nc;
    for (int k = t; k < K; k += 256)
        zin[k] = inB ? b2f(inB[(size_t)g * row_stride + k])
                     : inF[(size_t)g * row_stride + k];
    __syncthreads();
    const int klen = K >> 2;
    const int kb = kq * klen;
    float acc = 0.f;
    #pragma unroll 8
    for (int k = 0; k < klen; k++)
        acc = fmaf(zin[kb + k], W[(size_t)(kb + k) * N + n], acc);
    red[t] = acc;
    __syncthreads();
    if (kq == 0) {
        float v = red[nc] + red[nc + 64] + red[nc + 128] + red[nc + 192] + bias[n];
        if (act) v = gelu_f(v);
        out[(size_t)g * N + n] = v;
    }
}

// ---------------- fused: pool stage 1 (blocks 0..511) + head lin1 (512..1535) ----------------
__global__ __launch_bounds__(256) void k_pe1(const bf16* __restrict__ hb,
                                             float* __restrict__ part,
                                             const float* __restrict__ lin1w,
                                             const float* __restrict__ lin1b,
                                             float* __restrict__ t1, int PG) {
    __shared__ float zin[256];
    __shared__ float red[256];
    int bx = blockIdx.x;
    if (bx < 512) {
        int g = bx >> 3, p = bx & 7, c = threadIdx.x;
        int rows_per = PG / 8;
        const bf16* base = hb + ((size_t)g * PG + (size_t)p * rows_per) * 256;
        float acc = 0.f;
        for (int r = 0; r < rows_per; r++) acc += b2f(base[(size_t)r * 256 + c]);
        part[((size_t)g * 8 + p) * 256 + c] = acc;
    } else {
        int b = bx - 512;
        head_body(hb, nullptr, lin1w, lin1b, t1, 256, 1024,
                  (long long)PG * 256, 1, b >> 4, b & 15, zin, red);
    }
}

// ---------------- fused: pool stage 2 (blocks 0..63) + head lin2 (64..319) ----------------
__global__ __launch_bounds__(256) void k_pe2(const float* __restrict__ part,
                                             float* __restrict__ outPool, int PG,
                                             const float* __restrict__ t1,
                                             const float* __restrict__ lin2w,
                                             const float* __restrict__ lin2b,
                                             float* __restrict__ t2) {
    __shared__ float zin[1024];
    __shared__ float red[256];
    int bx = blockIdx.x;
    if (bx < 64) {
        int g = bx, c = threadIdx.x;
        float acc = 0.f;
        for (int p = 0; p < 8; p++) acc += part[((size_t)g * 8 + p) * 256 + c];
        outPool[g * 256 + c] = acc / (float)PG;
    } else {
        int b = bx - 64;
        head_body(nullptr, t1, lin2w, lin2b, t2, 1024, 256,
                  1024, 0, b >> 2, b & 3, zin, red);
    }
}

// ---------------- final head layer ----------------
__global__ __launch_bounds__(256) void k_fin(const float* __restrict__ t2,
                                             const float* __restrict__ finw,
                                             const float* __restrict__ finb,
                                             float* __restrict__ out) {
    __shared__ float zin[256];
    __shared__ float red[256];
    head_body(nullptr, t2, finw, finb, out, 256, 512,
              256, 0, blockIdx.x, blockIdx.y, zin, red);
}

extern "C" void kernel_launch(void* const* d_in, const int* in_sizes, int n_in,
                              void* d_out, int out_size, void* d_ws, size_t ws_size,
                              hipStream_t stream) {
    const float* x     = (const float*)d_in[0];
    const int*   ei    = (const int*)d_in[1];
    const float* w1_l  = (const float*)d_in[4];
    const float* b1_l  = (const float*)d_in[5];
    const float* w1_r  = (const float*)d_in[6];
    const float* b1_r  = (const float*)d_in[7];
    const float* att1  = (const float*)d_in[8];
    const float* bias1 = (const float*)d_in[9];
    const float* w2_l  = (const float*)d_in[10];
    const float* b2_l  = (const float*)d_in[11];
    const float* w2_r  = (const float*)d_in[12];
    const float* b2_r  = (const float*)d_in[13];
    const float* att2  = (const float*)d_in[14];
    const float* bias2 = (const float*)d_in[15];
    const float* lin1w = (const float*)d_in[16];
    const float* lin1b = (const float*)d_in[17];
    const float* lin2w = (const float*)d_in[18];
    const float* lin2b = (const float*)d_in[19];
    const float* finw  = (const float*)d_in[20];
    const float* finb  = (const float*)d_in[21];

    const int N  = in_sizes[0] / 256;   // 32768
    const int E  = in_sizes[1] / 2;     // 524288
    const int NG = 64;
    const int PG = N / NG;              // 512

    // workspace layout (~58 MiB)
    char* ws = (char*)d_ws;
    size_t off = 0;
    bf16* xlr = (bf16*)(ws + off); off += (size_t)N * 512 * 2;    // 32 MiB [xl|xr]
    bf16* hb  = (bf16*)(ws + off); off += (size_t)N * 256 * 2;    // 16 MiB (h1 then h2)
    bf16* wt  = (bf16*)(ws + off); off += 2 * 512 * 256 * 2;      // 512 KiB both layers' Wt
    int* cnt  = (int*)(ws + off); off += (size_t)N * 4;           // in-degree
    int* col  = (int*)(ws + off); off += (size_t)N * 64 * 4;      // 8 MiB bucket CSR
    float* pws = (float*)(ws + off); off += (size_t)NG * 8 * 256 * 4;  // pool partials
    float* t1  = (float*)(ws + off); off += (size_t)NG * 1024 * 4;
    float* t2  = (float*)(ws + off); off += (size_t)NG * 256 * 4;

    // bf16 copy of x aliases hb: dead until k_agg writes h1 (strictly after GEMM1 reads xb)
    bf16* xb = hb;

    const int* srcv = ei;
    const int* dstv = ei + E;

    // --- bucket scatter + weight transposes + x->bf16 (one launch) ---
    hipMemsetAsync(cnt, 0, (size_t)N * 4, stream);
    k_tr_scatter<<<512 + 1024 + 1024, 256, 0, stream>>>(dstv, srcv, cnt, col, E,
                                                        w1_l, w1_r, w2_l, w2_r, wt,
                                                        x, xb);

    // --- layer 1 ---
    dim3 gg(4, N / 128);
    k_gemm<<<gg, 256, 0, stream>>>(xb, wt, b1_l, b1_r, xlr, 256);
    k_agg<<<N / 2, 128, 0, stream>>>(xlr, att1, cnt, col, bias1, hb, 1);  // + GELU

    // --- layer 2 (A = h1 bf16) ---
    k_gemm<<<gg, 256, 0, stream>>>(hb, wt + 512 * 256, b2_l, b2_r, xlr, 256);
    k_agg<<<N / 2, 128, 0, stream>>>(xlr, att2, cnt, col, bias2, hb, 0);  // h2

    float* outp = (float*)d_out;
    // --- pool1 + head lin1 (one launch) ---
    k_pe1<<<512 + 1024, 256, 0, stream>>>(hb, pws, lin1w, lin1b, t1, PG);
    // --- pool2 (-> d_out[64*512..]) + head lin2 (one launch) ---
    k_pe2<<<64 + 256, 256, 0, stream>>>(pws, outp + 64 * 512, PG, t1, lin2w, lin2b, t2);
    // --- final head layer -> d_out[0..64*512) ---
    dim3 gf(NG, 512 / 64);
    k_fin<<<gf, 256, 0, stream>>>(t2, finw, finb, outp);
}

// Round 8
// 298.353 us; speedup vs baseline: 1.0884x; 1.0884x over previous
//
#include <hip/hip_runtime.h>
#include <hip/hip_bf16.h>
#include <stdint.h>

typedef __attribute__((ext_vector_type(8))) short short8;
typedef __attribute__((ext_vector_type(4))) float floatx4;
typedef __attribute__((ext_vector_type(2))) float floatx2;
typedef __attribute__((ext_vector_type(2))) int intx2;
typedef __hip_bfloat16 bf16;

__device__ __forceinline__ float b2f(bf16 v) { return __bfloat162float(v); }
__device__ __forceinline__ bf16 f2b(float v) { return __float2bfloat16(v); }
__device__ __forceinline__ float gelu_f(float v) {
    return 0.5f * v * (1.0f + erff(v * 0.70710678118654752f));
}
// two packed bf16 (one dword) -> two fp32, exact (<<16)
__device__ __forceinline__ floatx2 cvt2(unsigned v) {
    floatx2 r;
    r.x = __uint_as_float(v << 16);
    r.y = __uint_as_float(v & 0xffff0000u);
    return r;
}
// VALU-rate cross-lane add via DPP (no LGKM). CTRL: 0xB1=quad xor1, 0x4E=quad xor2,
// 0x141=row_half_mirror (cross-quad within 8-lane group; groups are 8-aligned).
template <int CTRL>
__device__ __forceinline__ float dpp_add(float v) {
    int x = __builtin_amdgcn_update_dpp(0, __float_as_int(v), CTRL, 0xf, 0xf, true);
    return v + __int_as_float(x);
}
// full-wave half sum at VALU rate: v[l] + v[l^32] for every lane.
__device__ __forceinline__ float sum_halves(float v) {
#if __has_builtin(__builtin_amdgcn_permlane32_swap)
    intx2 r = __builtin_amdgcn_permlane32_swap(__float_as_int(v), __float_as_int(v),
                                               false, false);
    return __int_as_float(r.x) + __int_as_float(r.y);
#else
    return v + __shfl_xor(v, 32, 64);
#endif
}

#define GLD_LDS16(gptr, lptr) \
  __builtin_amdgcn_global_load_lds((const __attribute__((address_space(1))) void*)(gptr), \
                                   (__attribute__((address_space(3))) void*)(lptr), 16, 0, 0)

// NOTE (R12): cooperative grid.sync() costs ~60us each here -- never fuse via grid.sync.
// NOTE (R15): GEMM LDS conflicts: fragment reads, fixed by XOR-swizzled 16B chunks
// (physical slot = logical ^ (row&7)); global_load_lds dest is linear, so swizzle the
// SOURCE k-offset.
// NOTE (R16): x pre-converted to bf16; GEMM = bf16 global_load_lds path; GEMM epilogue
// in two 64-row halves -> LDS exactly 32 KB.
// NOTE (R17/R20b, FAILED): extra per-lane state in k_agg loop (prefetch regs or
// 16ch/lane) kills it -- occupancy/ILP loss > latency gain.
// NOTE (R18, FAILED): node-grain work-steal = 32768 same-address atomics = 460us wall.
// NOTE (R19): 128-thread blocks; k_agg is instruction-issue-bound (VALU ~71%).
// NOTE (R21): leaky=max(u,0.2u); att pre-scaled by log2e -> raw v_exp_f32. KEEP.
// NOTE (R22): bucket CSR (64 slots/node, atomic return IS the slot) deletes
// scan/rank/fill. KEEP. But standalone scatter kernel = 49us of EXPOSED latency
// (VALU 0.8%) -- the scatter must stay overlapped with GEMM1 (R23). cnt zeroing
// folded into k_tr (drops the memset dispatch).

// ---------------- pre-pass: weight transposes (0..1023) + x->bf16 (1024..2047) + cnt=0 ----------------
__global__ void k_tr(const float* __restrict__ Wl1, const float* __restrict__ Wr1,
                     const float* __restrict__ Wl2, const float* __restrict__ Wr2,
                     bf16* __restrict__ Wt,
                     const float* __restrict__ x, bf16* __restrict__ xb,
                     int* __restrict__ cnt) {
    int bx = blockIdx.x;
    if (bx < 1024) {
        int r = bx & 255, half = (bx >> 8) & 1, layer = bx >> 9;
        int c = threadIdx.x;
        const float* W = layer ? (half ? Wr2 : Wl2) : (half ? Wr1 : Wl1);
        Wt[(size_t)(layer * 512 + half * 256 + c) * 256 + r] = f2b(W[r * 256 + c]);
    } else if (bx < 2048) {
        // x (32768x256 fp32) -> bf16, 32 contiguous floats per thread
        int b = bx - 1024;
        size_t base = ((size_t)b * 256 + threadIdx.x) * 32;
        const float4* xin = (const float4*)(x + base);
        #pragma unroll
        for (int q = 0; q < 4; q++) {
            float4 a = xin[2 * q];
            float4 c = xin[2 * q + 1];
            bf16 t[8] = {f2b(a.x), f2b(a.y), f2b(a.z), f2b(a.w),
                         f2b(c.x), f2b(c.y), f2b(c.z), f2b(c.w)};
            *(short8*)(xb + base + q * 8) = *(const short8*)t;
        }
    } else {
        // zero cnt (32768 ints; 128 blocks x 256 threads)
        cnt[(bx - 2048) * 256 + threadIdx.x] = 0;
    }
}

// ---------------- GEMM tile body: C[M,512] = A[M,K] @ Bt[512,K]^T + bias ----------------
// 128x128 tile, BK=64, XOR-swizzled LDS (physical 16B chunk = logical ^ (row&7)).
// bf16 A only (global_load_lds both operands). LDS = 32768 B exactly (5 blocks/CU).
__device__ __forceinline__ void gemm_body(const bf16* __restrict__ A,
                                          const bf16* __restrict__ Bt,
                                          const float* __restrict__ biasL,
                                          const float* __restrict__ biasR,
                                          bf16* __restrict__ C,
                                          int K, int m0, int n0,
                                          bf16* __restrict__ smem) {
    bf16* As = smem;
    bf16* Bs = smem + 8192;
    const int tid  = threadIdx.x;
    const int wave = tid >> 6;
    const int lane = tid & 63;
    const int quad = lane >> 4;
    const int l16  = lane & 15;
    const int wm = (wave & 1) * 64;
    const int wn = (wave >> 1) * 64;
    // source k-offset for swizzled global_load_lds staging (dest slot lane&7, row lane>>3)
    const int scole = ((lane & 7) ^ (lane >> 3)) * 8;
    const int srow  = lane >> 3;

    floatx4 acc[4][4] = {};

    for (int k0 = 0; k0 < K; k0 += 64) {
        #pragma unroll
        for (int i = 0; i < 4; i++) {
            int chunk = i * 4 + wave;                 // 16 chunks of 1 KB (8 rows) each
            int row = chunk * 8 + srow;
            GLD_LDS16(A + (size_t)(m0 + row) * K + k0 + scole,
                      (char*)As + chunk * 1024 + lane * 16);
            GLD_LDS16(Bt + (size_t)(n0 + row) * K + k0 + scole,
                      (char*)Bs + chunk * 1024 + lane * 16);
        }
        __syncthreads();
        #pragma unroll
        for (int ks = 0; ks < 2; ks++) {
            short8 af[4], bfr[4];
            int pk = ((ks * 4 + quad) ^ (l16 & 7)) * 8;   // swizzled fragment k-offset
            #pragma unroll
            for (int i = 0; i < 4; i++) {
                af[i]  = *(const short8*)&As[(wm + i * 16 + l16) * 64 + pk];
                bfr[i] = *(const short8*)&Bs[(wn + i * 16 + l16) * 64 + pk];
            }
            #pragma unroll
            for (int i = 0; i < 4; i++)
                #pragma unroll
                for (int j = 0; j < 4; j++)
                    acc[i][j] = __builtin_amdgcn_mfma_f32_16x16x32_bf16(af[i], bfr[j], acc[i][j], 0, 0, 0);
        }
        __syncthreads();
    }

    // C/D layout: col = lane&15, row = quad*4 + reg  [verified m89/m91]
    // Two 64-row halves through a 64x136 LDS buffer (fits in As+Bs region).
    float bvj[4];
    #pragma unroll
    for (int j = 0; j < 4; j++) {
        int gcol = n0 + wn + j * 16 + l16;
        bvj[j] = (gcol < 256) ? biasL[gcol] : biasR[gcol - 256];
    }
    #pragma unroll
    for (int h = 0; h < 2; h++) {
        if ((wave & 1) == h) {
            #pragma unroll
            for (int j = 0; j < 4; j++) {
                int lcol = wn + j * 16 + l16;
                #pragma unroll
                for (int i = 0; i < 4; i++)
                    #pragma unroll
                    for (int r = 0; r < 4; r++)
                        smem[(i * 16 + quad * 4 + r) * 136 + lcol] = f2b(acc[i][j][r] + bvj[j]);
            }
        }
        __syncthreads();
        {
            int rl = tid >> 4;
            int cs = (tid & 15) * 8;
            #pragma unroll
            for (int p = 0; p < 4; p++) {
                int row = p * 16 + rl;
                short8 v = *(const short8*)&smem[row * 136 + cs];
                *(short8*)(C + (size_t)(m0 + h * 64 + row) * 512 + n0 + cs) = v;
            }
        }
        if (h == 0) __syncthreads();
    }
}

// ---------------- union dispatch: bucket scatter + layer-1 GEMM (roles interleaved) ----------------
__global__ __launch_bounds__(256) void k_scatter_gemm(const int* __restrict__ src,
                                                      const int* __restrict__ dst,
                                                      int* __restrict__ cnt,
                                                      int* __restrict__ col, int E,
                                                      const bf16* __restrict__ A,
                                                      const bf16* __restrict__ Bt,
                                                      const float* __restrict__ biasL,
                                                      const float* __restrict__ biasR,
                                                      bf16* __restrict__ C, int K) {
    __shared__ bf16 smem[16384];
    int bx = blockIdx.x;
    int rem = bx % 3;
    if (rem == 2) {
        int g = (bx / 3) * 256 + threadIdx.x;
        if (g * 4 < E) {
            int4 d = ((const int4*)dst)[g];
            int4 s = ((const int4*)src)[g];
            int rk;
            rk = atomicAdd(&cnt[d.x], 1); if (rk < 64) col[(d.x << 6) + rk] = s.x;
            rk = atomicAdd(&cnt[d.y], 1); if (rk < 64) col[(d.y << 6) + rk] = s.y;
            rk = atomicAdd(&cnt[d.z], 1); if (rk < 64) col[(d.z << 6) + rk] = s.z;
            rk = atomicAdd(&cnt[d.w], 1); if (rk < 64) col[(d.w << 6) + rk] = s.w;
        }
    } else {
        int gid = (bx / 3) * 2 + rem;
        int n0 = (gid & 3) * 128;
        int m0 = (gid >> 2) * 128;
        gemm_body(A, Bt, biasL, biasR, C, K, m0, n0, smem);
    }
}

// ---------------- standalone GEMM (layer 2, bf16 A) ----------------
__global__ __launch_bounds__(256) void k_gemm2(const bf16* __restrict__ A,
                                               const bf16* __restrict__ Bt,
                                               const float* __restrict__ biasL,
                                               const float* __restrict__ biasR,
                                               bf16* __restrict__ C, int K) {
    __shared__ bf16 smem[16384];
    gemm_body(A, Bt, biasL, biasR, C, K, blockIdx.y * 128, blockIdx.x * 128, smem);
}

// ---------------- GATv2 aggregation: half-wave per edge, 8 ch/lane, packed fp32 math ----------
// 128-thread blocks, one wave per dst node. Lanes 0-31 = item a, 32-63 = item b of each
// pair. Within a half: 8 lanes per head (hl>>3), 8 channels per lane ((hl&7)*8).
// Item 0 = self-loop. Bucket CSR: node i's in-edges at col[i*64 .. i*64+deg).
// Max-free softmax (logits bounded). leaky = max(u, 0.2u); att pre-scaled by log2(e)
// so p = v_exp_f32(l) = e^logit. Reduce via DPP; half-combine via permlane32_swap.
__global__ __launch_bounds__(128) void k_agg(const bf16* __restrict__ xlr,
                                             const float* __restrict__ att,
                                             const int* __restrict__ cnt,
                                             const int* __restrict__ col,
                                             const float* __restrict__ bias,
                                             bf16* __restrict__ out, int do_gelu) {
    int wave = threadIdx.x >> 6, lane = threadIdx.x & 63;
    int i = blockIdx.x * 2 + wave;
    int hl = lane & 31;
    int half = lane >> 5;
    unsigned f = (hl >> 3) * 64 + (hl & 7) * 8;

    const float LOG2E = 1.4426950408889634f;
    const floatx2 c02 = {0.2f, 0.2f};
    floatx2 attv[4], xrv[4];
    {
        floatx4 a0 = *(const floatx4*)(att + f);
        floatx4 a1 = *(const floatx4*)(att + f + 4);
        attv[0] = (floatx2){LOG2E * a0[0], LOG2E * a0[1]};
        attv[1] = (floatx2){LOG2E * a0[2], LOG2E * a0[3]};
        attv[2] = (floatx2){LOG2E * a1[0], LOG2E * a1[1]};
        attv[3] = (floatx2){LOG2E * a1[2], LOG2E * a1[3]};
        unsigned raw[4];
        *(uint4*)raw = *(const uint4*)(xlr + ((unsigned)i * 512u + 256u + f));
        #pragma unroll
        for (int k = 0; k < 4; k++) xrv[k] = cvt2(raw[k]);
    }

    int deg = cnt[i];
    deg = deg > 64 ? 64 : deg;
    int e0 = i << 6;
    int total = 1 + deg;   // self + in-edges

    int src_c = i;
    if (half == 1 && total > 1) src_c = col[e0];
    unsigned g_cur[4];
    *(uint4*)g_cur = *(const uint4*)(xlr + ((unsigned)src_c * 512u + f));
    int t1 = 2 + half;
    int src_n = (t1 < total) ? col[e0 + t1 - 1] : i;

    float s = 0.f;
    floatx2 acc2[4] = {};

    for (int base = 0; base < total; base += 2) {
        unsigned g_nxt[4];
        *(uint4*)g_nxt = *(const uint4*)(xlr + ((unsigned)src_n * 512u + f));
        int t2 = base + 4 + half;
        int src_n2 = (t2 < total) ? col[e0 + t2 - 1] : i;
        bool valid = (base + half) < total;
        floatx2 xv[4], l2 = {0.f, 0.f};
        #pragma unroll
        for (int k = 0; k < 4; k++) {
            xv[k] = cvt2(g_cur[k]);
            floatx2 u = xv[k] + xrv[k];                    // v_pk_add_f32
            floatx2 lr = __builtin_elementwise_max(u, u * c02);  // leaky: pk_mul + pk_max
            l2 += lr * attv[k];                            // v_pk_fma_f32 (att * log2e)
        }
        float l = l2.x + l2.y;
        l = dpp_add<0xB1>(l);     // xor1 within quad
        l = dpp_add<0x4E>(l);     // xor2 within quad
        l = dpp_add<0x141>(l);    // cross-quad within 8-lane group
        float p;
        asm("v_exp_f32 %0, %1" : "=v"(p) : "v"(l));   // 2^(logit*log2e) = e^logit
        p = valid ? p : 0.f;
        s += p;
        floatx2 p2 = {p, p};
        #pragma unroll
        for (int k = 0; k < 4; k++) acc2[k] += p2 * xv[k];   // v_pk_fma_f32
        #pragma unroll
        for (int k = 0; k < 4; k++) g_cur[k] = g_nxt[k];
        src_n = src_n2;
    }

    // combine the two halves (VALU-rate, no LGKM)
    s = sum_halves(s);
    #pragma unroll
    for (int k = 0; k < 4; k++) {
        acc2[k].x = sum_halves(acc2[k].x);
        acc2[k].y = sum_halves(acc2[k].y);
    }

    if (half == 0) {
        float inv = 1.0f / (s + 1e-16f);
        bf16 ov[8];
        #pragma unroll
        for (int k = 0; k < 4; k++) {
            float v0 = acc2[k].x * inv + bias[f + 2 * k];
            float v1 = acc2[k].y * inv + bias[f + 2 * k + 1];
            if (do_gelu) { v0 = gelu_f(v0); v1 = gelu_f(v1); }
            ov[2 * k]     = f2b(v0);
            ov[2 * k + 1] = f2b(v1);
        }
        *(short8*)(out + ((unsigned)i * 256u + f)) = *(const short8*)ov;
    }
}

// ---------------- shared head-layer body (block = one (graph, 64-col chunk)) ----------------
__device__ __forceinline__ void head_body(const bf16* __restrict__ inB,
                                          const float* __restrict__ inF,
                                          const float* __restrict__ W,
                                          const float* __restrict__ bias,
                                          float* __restrict__ out,
                                          int K, int N, long long row_stride, int act,
                                          int g, int chunk, float* zin, float* red) {
    int t = threadIdx.x;
    int nc = t & 63;
    int kq = t >> 6;
    int n = chunk * 64 + nc;
    for (int k = t; k < K; k += 256)
        zin[k] = inB ? b2f(inB[(size_t)g * row_stride + k])
                     : inF[(size_t)g * row_stride + k];
    __syncthreads();
    const int klen = K >> 2;
    const int kb = kq * klen;
    float acc = 0.f;
    #pragma unroll 8
    for (int k = 0; k < klen; k++)
        acc = fmaf(zin[kb + k], W[(size_t)(kb + k) * N + n], acc);
    red[t] = acc;
    __syncthreads();
    if (kq == 0) {
        float v = red[nc] + red[nc + 64] + red[nc + 128] + red[nc + 192] + bias[n];
        if (act) v = gelu_f(v);
        out[(size_t)g * N + n] = v;
    }
}

// ---------------- fused: pool stage 1 (blocks 0..511) + head lin1 (512..1535) ----------------
__global__ __launch_bounds__(256) void k_pe1(const bf16* __restrict__ hb,
                                             float* __restrict__ part,
                                             const float* __restrict__ lin1w,
                                             const float* __restrict__ lin1b,
                                             float* __restrict__ t1, int PG) {
    __shared__ float zin[256];
    __shared__ float red[256];
    int bx = blockIdx.x;
    if (bx < 512) {
        int g = bx >> 3, p = bx & 7, c = threadIdx.x;
        int rows_per = PG / 8;
        const bf16* base = hb + ((size_t)g * PG + (size_t)p * rows_per) * 256;
        float acc = 0.f;
        for (int r = 0; r < rows_per; r++) acc += b2f(base[(size_t)r * 256 + c]);
        part[((size_t)g * 8 + p) * 256 + c] = acc;
    } else {
        int b = bx - 512;
        head_body(hb, nullptr, lin1w, lin1b, t1, 256, 1024,
                  (long long)PG * 256, 1, b >> 4, b & 15, zin, red);
    }
}

// ---------------- fused: pool stage 2 (blocks 0..63) + head lin2 (64..319) ----------------
__global__ __launch_bounds__(256) void k_pe2(const float* __restrict__ part,
                                             float* __restrict__ outPool, int PG,
                                             const float* __restrict__ t1,
                                             const float* __restrict__ lin2w,
                                             const float* __restrict__ lin2b,
                                             float* __restrict__ t2) {
    __shared__ float zin[1024];
    __shared__ float red[256];
    int bx = blockIdx.x;
    if (bx < 64) {
        int g = bx, c = threadIdx.x;
        float acc = 0.f;
        for (int p = 0; p < 8; p++) acc += part[((size_t)g * 8 + p) * 256 + c];
        outPool[g * 256 + c] = acc / (float)PG;
    } else {
        int b = bx - 64;
        head_body(nullptr, t1, lin2w, lin2b, t2, 1024, 256,
                  1024, 0, b >> 2, b & 3, zin, red);
    }
}

// ---------------- final head layer ----------------
__global__ __launch_bounds__(256) void k_fin(const float* __restrict__ t2,
                                             const float* __restrict__ finw,
                                             const float* __restrict__ finb,
                                             float* __restrict__ out) {
    __shared__ float zin[256];
    __shared__ float red[256];
    head_body(nullptr, t2, finw, finb, out, 256, 512,
              256, 0, blockIdx.x, blockIdx.y, zin, red);
}

extern "C" void kernel_launch(void* const* d_in, const int* in_sizes, int n_in,
                              void* d_out, int out_size, void* d_ws, size_t ws_size,
                              hipStream_t stream) {
    const float* x     = (const float*)d_in[0];
    const int*   ei    = (const int*)d_in[1];
    const float* w1_l  = (const float*)d_in[4];
    const float* b1_l  = (const float*)d_in[5];
    const float* w1_r  = (const float*)d_in[6];
    const float* b1_r  = (const float*)d_in[7];
    const float* att1  = (const float*)d_in[8];
    const float* bias1 = (const float*)d_in[9];
    const float* w2_l  = (const float*)d_in[10];
    const float* b2_l  = (const float*)d_in[11];
    const float* w2_r  = (const float*)d_in[12];
    const float* b2_r  = (const float*)d_in[13];
    const float* att2  = (const float*)d_in[14];
    const float* bias2 = (const float*)d_in[15];
    const float* lin1w = (const float*)d_in[16];
    const float* lin1b = (const float*)d_in[17];
    const float* lin2w = (const float*)d_in[18];
    const float* lin2b = (const float*)d_in[19];
    const float* finw  = (const float*)d_in[20];
    const float* finb  = (const float*)d_in[21];

    const int N  = in_sizes[0] / 256;   // 32768
    const int E  = in_sizes[1] / 2;     // 524288
    const int NG = 64;
    const int PG = N / NG;              // 512

    // workspace layout (~58 MiB)
    char* ws = (char*)d_ws;
    size_t off = 0;
    bf16* xlr = (bf16*)(ws + off); off += (size_t)N * 512 * 2;    // 32 MiB [xl|xr]
    bf16* hb  = (bf16*)(ws + off); off += (size_t)N * 256 * 2;    // 16 MiB (h1 then h2)
    bf16* wt  = (bf16*)(ws + off); off += 2 * 512 * 256 * 2;      // 512 KiB both layers' Wt
    int* cnt  = (int*)(ws + off); off += (size_t)N * 4;           // in-degree
    int* col  = (int*)(ws + off); off += (size_t)N * 64 * 4;      // 8 MiB bucket CSR
    float* pws = (float*)(ws + off); off += (size_t)NG * 8 * 256 * 4;  // pool partials
    float* t1  = (float*)(ws + off); off += (size_t)NG * 1024 * 4;
    float* t2  = (float*)(ws + off); off += (size_t)NG * 256 * 4;

    // bf16 copy of x aliases hb: dead until k_agg writes h1 (strictly after GEMM1 reads xb)
    bf16* xb = hb;

    const int* srcv = ei;
    const int* dstv = ei + E;

    // --- pre-pass: weight transposes + x->bf16 + cnt=0 (one launch, no memset) ---
    k_tr<<<1024 + 1024 + 128, 256, 0, stream>>>(w1_l, w1_r, w2_l, w2_r, wt, x, xb, cnt);

    // --- bucket scatter + layer-1 GEMM (union launch, scatter hidden under MFMA) ---
    k_scatter_gemm<<<512 + 1024, 256, 0, stream>>>(srcv, dstv, cnt, col, E,
                                                   xb, wt, b1_l, b1_r, xlr, 256);
    k_agg<<<N / 2, 128, 0, stream>>>(xlr, att1, cnt, col, bias1, hb, 1);  // + GELU

    // --- layer 2 (A = h1 bf16) ---
    dim3 gg(4, N / 128);
    k_gemm2<<<gg, 256, 0, stream>>>(hb, wt + 512 * 256, b2_l, b2_r, xlr, 256);
    k_agg<<<N / 2, 128, 0, stream>>>(xlr, att2, cnt, col, bias2, hb, 0);  // h2

    float* outp = (float*)d_out;
    // --- pool1 + head lin1 (one launch) ---
    k_pe1<<<512 + 1024, 256, 0, stream>>>(hb, pws, lin1w, lin1b, t1, PG);
    // --- pool2 (-> d_out[64*512..]) + head lin2 (one launch) ---
    k_pe2<<<64 + 256, 256, 0, stream>>>(pws, outp + 64 * 512, PG, t1, lin2w, lin2b, t2);
    // --- final head layer -> d_out[0..64*512) ---
    dim3 gf(NG, 512 / 64);
    k_fin<<<gf, 256, 0, stream>>>(t2, finw, finb, outp);
}